// Round 9
// baseline (1846.760 us; speedup 1.0000x reference)
//
#include <hip/hip_runtime.h>

// RNN_16492674416646: h_t = tanh(x_t W_ih^T + b_ih + b_hh + h_{t-1} W_hh^T),
// out_t = h_t W_out^T + b_out. T=2048, B=128, IN=2, H=200, OUT=1, fp32.
//
// One block per batch element (128 blocks, 1024 threads = 16 waves).
// Cross-round evidence (R2,R3,R5,R7,R8 all ~1400-1700 cyc/step): the
// allocator keeps only ~50-60 of our floats in arch VGPRs (VGPR_Count
// 40..88), parking the rest (AGPR copy churn on the FMA dep path; FETCH
// rules out memory refetch). R9: demand only 50 resident floats/thread.
//   wave = (s in [0,8) k-slice of 25, hf in {0,1} row-half)
//   lane g<50 owns rows {100hf+2g, +1} x k-slice [25s,25s+25) = 50 wts
//   amdgpu_waves_per_eu(4,4): 16 waves = exactly 1 block/CU, budget 128
//   VGPR -> 50 wts + ~30 overhead fits with slack; scalar asm pins are
//   free if values are already resident.
// Phase 2 on hf=0 waves (8x25 lanes); head drain (8-deep LDS ring) on
// hf=1 waves every 8th step -- both off the other half's critical path.

static constexpr int T = 2048;
static constexpr int B = 128;
static constexpr int H = 200;
static constexpr int KS = 25;      // k-slice width
static constexpr int NTHR = 1024;  // 16 waves

#define WLIST(X) X(0) X(1) X(2) X(3) X(4) X(5) X(6) X(7) X(8) X(9) \
    X(10) X(11) X(12) X(13) X(14) X(15) X(16) X(17) X(18) X(19) \
    X(20) X(21) X(22) X(23) X(24)

#define PINW(p) asm volatile("" : \
    "+v"(p##_0),  "+v"(p##_1),  "+v"(p##_2),  "+v"(p##_3),  "+v"(p##_4),  \
    "+v"(p##_5),  "+v"(p##_6),  "+v"(p##_7),  "+v"(p##_8),  "+v"(p##_9),  \
    "+v"(p##_10), "+v"(p##_11), "+v"(p##_12), "+v"(p##_13), "+v"(p##_14), \
    "+v"(p##_15), "+v"(p##_16), "+v"(p##_17), "+v"(p##_18), "+v"(p##_19), \
    "+v"(p##_20), "+v"(p##_21), "+v"(p##_22), "+v"(p##_23), "+v"(p##_24))

__global__ __attribute__((amdgpu_flat_work_group_size(NTHR, NTHR),
                          amdgpu_waves_per_eu(4, 4)))
void rnn_fused(const float* __restrict__ x,     // [T,B,2]
               const float* __restrict__ W_ih,  // [H,2]
               const float* __restrict__ W_hh,  // [H,H]
               const float* __restrict__ b_ih,  // [H]
               const float* __restrict__ b_hh,  // [H]
               const float* __restrict__ W_out, // [1,H]
               const float* __restrict__ b_out, // [1]
               float* __restrict__ out)         // [T,B]
{
    const int b    = blockIdx.x;
    const int tid  = threadIdx.x;
    const int w    = tid >> 6;          // wave id 0..15
    const int lane = tid & 63;
    const int s    = w >> 1;            // k-slice id 0..7
    const int hf   = w & 1;             // row-half 0..1
    const bool rowact = (lane < 50);
    const int g    = rowact ? lane : 49;   // clamp: harmless dup work
    const int j0   = 100 * hf + 2 * g;     // first of 2 owned rows
    const int k0   = KS * s;

    __shared__ __align__(16) float ring[8][H];   // h history, slot = t&7
    __shared__ __align__(16) float part[8][H];   // per-k-slice partials
    __shared__ float xs[2 * T];                  // x column (16 KB)

    // --- one-time: 50 weights as NAMED SCALAR SSA values ---
    const float* ra = W_hh + (j0 + 0) * H + k0;
    const float* rb = W_hh + (j0 + 1) * H + k0;
#define DECLW(i) float wa_##i = ra[i]; float wb_##i = rb[i];
    WLIST(DECLW)
#undef DECLW

    // --- one-time: stage x[:, b, :] into LDS ---
    for (int idx = tid; idx < T; idx += NTHR) {
        const float2 v = *(const float2*)(x + (size_t)idx * (B * 2) + 2 * b);
        xs[2 * idx + 0] = v.x;
        xs[2 * idx + 1] = v.y;
    }

    // --- one-time: phase-2 constants; (hf==0, lane<25) owns jp=25s+lane
    const int jp = 25 * s + ((lane < 25) ? lane : 24);
    const float wih0 = W_ih[jp * 2 + 0];
    const float wih1 = W_ih[jp * 2 + 1];
    const float bias = b_ih[jp] + b_hh[jp];

    // --- one-time: head constants (hf==1 waves, every 8th step) ---
    const float wo0 = W_out[lane];
    const float wo1 = W_out[64 + lane];
    const float wo2 = W_out[128 + lane];
    const float wo3 = (lane < H - 192) ? W_out[192 + lane] : 0.f;
    const float bo  = b_out[0];

    if (tid < H) ring[7][tid] = 0.f;    // h_0 = 0 (step 0 reads slot 7)
    __syncthreads();

    float* op = out + b;

    for (int t = 0; t < T; ++t) {
        // pin weights: keeps them arch-VGPR-resident; free if already there
        PINW(wa); PINW(wb);

        const float x0 = xs[2 * t + 0];
        const float x1 = xs[2 * t + 1];

        // --- phase 1: h slice (1 ds_read_b32/wave) -> SGPR -> FMA ---
        const int hidx = (lane < KS) ? lane : 0;
        const float hval = ring[(t + 7) & 7][k0 + hidx];

        float a0 = 0.f, a1 = 0.f;       // 2 rows, 25-deep chains
#define FMASTEP(i) { \
        const float hs_ = __int_as_float( \
            __builtin_amdgcn_readlane(__float_as_int(hval), i)); \
        a0 = fmaf(wa_##i, hs_, a0); \
        a1 = fmaf(wb_##i, hs_, a1); }
        WLIST(FMASTEP)
#undef FMASTEP

        if (rowact) {
            float2 v; v.x = a0; v.y = a1;
            *(float2*)&part[s][j0] = v;             // b64, ~2-way (free)
        }
        __syncthreads();

        // --- phase 2 (hf==0 waves, lanes 0..24): j = 25s+lane ---
        if (hf == 0 && lane < 25) {
            const float p01 = part[0][jp] + part[1][jp];
            const float p23 = part[2][jp] + part[3][jp];
            const float p45 = part[4][jp] + part[5][jp];
            const float p67 = part[6][jp] + part[7][jp];
            const float sum = (p01 + p23) + (p45 + p67);
            const float pre = sum + fmaf(x0, wih0, fmaf(x1, wih1, bias));
            // tanh(x) = 1 - 2/(e^{2x}+1); saturates correctly at +-inf
            const float e = __expf(2.f * pre);
            ring[t & 7][jp] = 1.f - 2.f / (e + 1.f);
        }
        __syncthreads();

        // --- head (hf==1 waves), every 8 steps: wave s drains slot s ---
        // Slot s is next rewritten in phase 2 of step t+1+s, which is
        // after a barrier this wave only passes post-drain -> safe.
        if (hf == 1 && (t & 7) == 7) {
            const int l3 = (lane < H - 192) ? lane : 0;
            float v = ring[s][lane] * wo0 + ring[s][64 + lane] * wo1
                    + ring[s][128 + lane] * wo2 + ring[s][192 + l3] * wo3;
#pragma unroll
            for (int off = 32; off > 0; off >>= 1)
                v += __shfl_down(v, off, 64);
            if (lane == 0) op[(size_t)(t - 7 + s) * B] = v + bo;
        }
    }
}

extern "C" void kernel_launch(void* const* d_in, const int* in_sizes, int n_in,
                              void* d_out, int out_size, void* d_ws, size_t ws_size,
                              hipStream_t stream) {
    const float* x     = (const float*)d_in[0];
    const float* W_ih  = (const float*)d_in[1];
    const float* W_hh  = (const float*)d_in[2];
    const float* b_ih  = (const float*)d_in[3];
    const float* b_hh  = (const float*)d_in[4];
    const float* W_out = (const float*)d_in[5];
    const float* b_out = (const float*)d_in[6];
    float* out = (float*)d_out;

    rnn_fused<<<B, NTHR, 0, stream>>>(x, W_ih, W_hh, b_ih, b_hh, W_out, b_out, out);
}

// Round 10
// 1681.976 us; speedup vs baseline: 1.0980x; 1.0980x over previous
//
#include <hip/hip_runtime.h>

// RNN_16492674416646: h_t = tanh(x_t W_ih^T + b_ih + b_hh + h_{t-1} W_hh^T),
// out_t = h_t W_out^T + b_out. T=2048, B=128, IN=2, H=200, OUT=1, fp32.
//
// R10: MFMA pivot. R2-R9 showed the VALU family is exhausted: demanding
// fp32 weights in arch VGPRs always produces AGPR<->VGPR copy churn
// (~2x instr bloat), and LDS-resident weights floor at 160KB/85B/cyc ~
// 1900 cyc/step. MFMA reads AGPRs natively -> the parking is free.
//
// One block per batch (128 blocks, 512 thr = 8 waves). Per step:
// y[n] = sum_k W[n][k] h[k] via mfma_f32_16x16x32_bf16, 13 n-tiles x
// 7 k-tiles (padded 224). Wave w owns n-tiles {w, w+8(if<13)}.
// Precision: split-bf16. h_hi -> A row 0 (lanes m=0), h_lo -> A row 1
// (lanes m=1); 2 mfmas per tile (B=W_hi, B=W_lo). y = D.row0 + D.row1
// = (W_hi+W_lo)(h_hi+h_lo): per-step rel err ~2^-17.
// Layouts (HW-verified): A[m=lane&15][k=(lane>>4)*8+j]; D col=lane&15,
// row=(lane>>4)*4+reg -> rows 0,1 = acc[0],acc[1] of lanes 0..15.
// h ring: 8 bf16 hi/lo slots; ONE barrier/step. Head drained every 8
// steps (waves 0-6 pre-barrier on stable slots 0-6, wave 7 post-barrier).

typedef short s8v __attribute__((ext_vector_type(8)));   // 8 x bf16 bits
typedef float f4v __attribute__((ext_vector_type(4)));

static constexpr int T = 2048;
static constexpr int B = 128;
static constexpr int H = 200;
static constexpr int NTHR = 512;
static constexpr int KT = 7;     // k-tiles of 32
static constexpr int HP = 224;   // padded H

__device__ __forceinline__ unsigned short f2bf(float f) {
    unsigned int u = __float_as_uint(f);            // RNE truncate to bf16
    unsigned int r = (u + 0x7FFFu + ((u >> 16) & 1u)) >> 16;
    return (unsigned short)r;
}
__device__ __forceinline__ float bf2f(unsigned short h) {
    return __uint_as_float(((unsigned int)h) << 16);
}

__global__ __attribute__((amdgpu_flat_work_group_size(NTHR, NTHR),
                          amdgpu_waves_per_eu(2, 2)))
void rnn_fused(const float* __restrict__ x,     // [T,B,2]
               const float* __restrict__ W_ih,  // [H,2]
               const float* __restrict__ W_hh,  // [H,H]
               const float* __restrict__ b_ih,  // [H]
               const float* __restrict__ b_hh,  // [H]
               const float* __restrict__ W_out, // [1,H]
               const float* __restrict__ b_out, // [1]
               float* __restrict__ out)         // [T,B]
{
    const int b    = blockIdx.x;
    const int tid  = threadIdx.x;
    const int w    = tid >> 6;       // wave id 0..7
    const int lane = tid & 63;
    const int m    = lane & 15;      // A-row / B-col / D-col index
    const int q    = lane >> 4;      // k-chunk (quad)

    __shared__ __align__(16) unsigned short hhi[8][HP];  // h ring, hi bf16
    __shared__ __align__(16) unsigned short hlo[8][HP];  // h ring, lo bf16
    __shared__ float xs[2 * T];                          // x column (16 KB)

    // zero the whole ring: slot 7 = h_0 = 0; pads [200,224) stay 0 forever
    for (int i = tid; i < 8 * HP; i += NTHR) {
        (&hhi[0][0])[i] = 0; (&hlo[0][0])[i] = 0;
    }
    // stage x[:, b, :]
    for (int idx = tid; idx < T; idx += NTHR) {
        const float2 v = *(const float2*)(x + (size_t)idx * (B * 2) + 2 * b);
        xs[2 * idx] = v.x; xs[2 * idx + 1] = v.y;
    }

    // --- loop-invariant B-fragments: B[k][n] = W_hh[n][k], split hi/lo ---
    // lane holds B[k = 8q+j (within k-tile)][n = 16*tile + m], j ascending.
    const int n_a  = 16 * w + m;          // tile0 col: <= 127, always valid
    const int n_b  = 16 * (w + 8) + m;    // tile1 col: may be >= 200
    const bool hasB = (w < 5);            // tiles 8..12 on waves 0..4
    s8v Bh0[KT], Bl0[KT], Bh1[KT], Bl1[KT];
#pragma unroll
    for (int kt = 0; kt < KT; ++kt) {
        s8v bh0{}, bl0{}, bh1{}, bl1{};
#pragma unroll
        for (int j = 0; j < 8; ++j) {
            const int ks = 32 * kt + 8 * q + j;
            const float w0 = (ks < H) ? W_hh[n_a * H + ks] : 0.f;
            const unsigned short h0 = f2bf(w0);
            bh0[j] = (short)h0;
            bl0[j] = (short)f2bf(w0 - bf2f(h0));
            const float w1 = (hasB && n_b < H && ks < H) ? W_hh[n_b * H + ks] : 0.f;
            const unsigned short h1 = f2bf(w1);
            bh1[j] = (short)h1;
            bl1[j] = (short)f2bf(w1 - bf2f(h1));
        }
        Bh0[kt] = bh0; Bl0[kt] = bl0; Bh1[kt] = bh1; Bl1[kt] = bl1;
    }

    // --- epilogue constants (lanes 0..15 own col n of their tiles) ---
    float wa0 = 0.f, wa1 = 0.f, ba = 0.f, wb0 = 0.f, wb1 = 0.f, bb = 0.f;
    if (q == 0) {
        wa0 = W_ih[n_a * 2]; wa1 = W_ih[n_a * 2 + 1];
        ba  = b_ih[n_a] + b_hh[n_a];
        if (hasB && n_b < H) {
            wb0 = W_ih[n_b * 2]; wb1 = W_ih[n_b * 2 + 1];
            bb  = b_ih[n_b] + b_hh[n_b];
        }
    }
    // --- head constants ---
    const float wo0 = W_out[lane];
    const float wo1 = W_out[64 + lane];
    const float wo2 = W_out[128 + lane];
    const float wo3 = (192 + lane < H) ? W_out[192 + lane] : 0.f;
    const float bo  = b_out[0];

    __syncthreads();

    float* op = out + b;

    auto drain = [&](int slot, int tout) {
        float v = (bf2f(hhi[slot][lane])       + bf2f(hlo[slot][lane]))       * wo0
                + (bf2f(hhi[slot][64 + lane])  + bf2f(hlo[slot][64 + lane]))  * wo1
                + (bf2f(hhi[slot][128 + lane]) + bf2f(hlo[slot][128 + lane])) * wo2;
        if (lane < 32)  // 192+lane <= 223; pads are zero, wo3 zero for n>=200
            v += (bf2f(hhi[slot][192 + lane]) + bf2f(hlo[slot][192 + lane])) * wo3;
#pragma unroll
        for (int off = 32; off > 0; off >>= 1)
            v += __shfl_down(v, off, 64);
        if (lane == 0) op[(size_t)tout * B] = v + bo;
    };

    for (int t = 0; t < T; ++t) {
        const float x0 = xs[2 * t], x1 = xs[2 * t + 1];
        const int sr = (t + 7) & 7;         // read slot (h_{t-1})
        const int sw = t & 7;               // write slot (h_t)

        // A fragment source: row m=0 <- h_hi, row m=1 <- h_lo, rows 2..15
        // <- h_hi (garbage rows land in ignored D rows). Broadcast b128.
        const unsigned short* hb = (m == 1) ? &hlo[sr][0] : &hhi[sr][0];

        f4v acc0 = {0.f, 0.f, 0.f, 0.f};
        f4v acc1 = {0.f, 0.f, 0.f, 0.f};
#pragma unroll
        for (int kt = 0; kt < KT; ++kt) {
            const s8v A = *(const s8v*)(hb + 32 * kt + 8 * q);
            acc0 = __builtin_amdgcn_mfma_f32_16x16x32_bf16(A, Bh0[kt], acc0, 0, 0, 0);
            acc0 = __builtin_amdgcn_mfma_f32_16x16x32_bf16(A, Bl0[kt], acc0, 0, 0, 0);
            if (hasB) {
                acc1 = __builtin_amdgcn_mfma_f32_16x16x32_bf16(A, Bh1[kt], acc1, 0, 0, 0);
                acc1 = __builtin_amdgcn_mfma_f32_16x16x32_bf16(A, Bl1[kt], acc1, 0, 0, 0);
            }
        }

        // --- epilogue: lanes 0..15 hold D rows 0,1 for col n = 16*tile+m ---
        if (q == 0) {
            {
                const float pre = (acc0[0] + acc0[1])
                                + fmaf(x0, wa0, fmaf(x1, wa1, ba));
                const float e  = __expf(2.f * pre);
                const float th = 1.f - 2.f / (e + 1.f);
                const unsigned short hi = f2bf(th);
                hhi[sw][n_a] = hi;
                hlo[sw][n_a] = f2bf(th - bf2f(hi));
            }
            if (hasB && n_b < H) {
                const float pre = (acc1[0] + acc1[1])
                                + fmaf(x0, wb0, fmaf(x1, wb1, bb));
                const float e  = __expf(2.f * pre);
                const float th = 1.f - 2.f / (e + 1.f);
                const unsigned short hi = f2bf(th);
                hhi[sw][n_b] = hi;
                hlo[sw][n_b] = f2bf(th - bf2f(hi));
            }
        }

        // --- head: every 8 steps drain the ring (slot j holds h_{t-7+j}) ---
        // slots 0..6 stable since earlier barriers -> drain pre-barrier;
        // slot 7 written this step -> wave 7 drains it post-barrier (next
        // rewrite of slot 7 is 7 barriers away).
        const bool dr = ((t & 7) == 7);
        if (dr && w < 7) drain(w, t - 7 + w);
        __syncthreads();
        if (dr && w == 7) drain(7, t);
    }
}

extern "C" void kernel_launch(void* const* d_in, const int* in_sizes, int n_in,
                              void* d_out, int out_size, void* d_ws, size_t ws_size,
                              hipStream_t stream) {
    const float* x     = (const float*)d_in[0];
    const float* W_ih  = (const float*)d_in[1];
    const float* W_hh  = (const float*)d_in[2];
    const float* b_ih  = (const float*)d_in[3];
    const float* b_hh  = (const float*)d_in[4];
    const float* W_out = (const float*)d_in[5];
    const float* b_out = (const float*)d_in[6];
    float* out = (float*)d_out;

    rnn_fused<<<B, NTHR, 0, stream>>>(x, W_ih, W_hh, b_ih, b_hh, W_out, b_out, out);
}